// Round 1
// baseline (1600.530 us; speedup 1.0000x reference)
//
#include <hip/hip_runtime.h>
#include <cstdint>

#define H_ 128
#define W_ 128
#define HW 16384

// ---------------------------------------------------------------------------
// conv3x3, NCHW, pad 1. Per block: 8 output channels (blockIdx.y), spatial
// tile 32 rows x 64 cols. Per thread: 8 pixels along W x 8 output channels.
// Weights staged in LDS as [ci*9+k][co8] for broadcast float4 reads.
// ACT: 0 = none, 1 = leaky_relu(0.1), 2 = conv4 epilogue (10*tanh / sigmoid)
// ---------------------------------------------------------------------------
template<int CIN_T, int COUT_T, int ACT>
__global__ __launch_bounds__(256)
void conv3x3_kern(const float* __restrict__ in, const float* __restrict__ wsrc,
                  const float* __restrict__ bias, float* __restrict__ out) {
    __shared__ float wlds[CIN_T * 9 * 8];
    const int tid = threadIdx.x;
    const int bx  = blockIdx.x;
    const int cog = blockIdx.y;
    const int b   = bx >> 3;
    const int t   = bx & 7;
    const int th  = (t >> 1) * 32;
    const int tw  = (t & 1) * 64;

    // stage weights: wlds[(ci*9+k)*8 + co8] = wsrc[(cog*8+co8)*CIN*9 + ci*9+k]
    for (int i = tid; i < CIN_T * 9 * 8; i += 256) {
        int co8 = i / (CIN_T * 9);
        int r   = i - co8 * (CIN_T * 9);
        wlds[r * 8 + co8] = wsrc[(cog * 8 + co8) * (CIN_T * 9) + r];
    }
    __syncthreads();

    const int rrow = tid >> 3;        // 0..31
    const int cg   = tid & 7;         // 0..7
    const int h    = th + rrow;
    const int w0   = tw + cg * 8;

    float acc[8][8];
    #pragma unroll
    for (int c = 0; c < 8; ++c) {
        float bv = bias[cog * 8 + c];
        #pragma unroll
        for (int p = 0; p < 8; ++p) acc[c][p] = bv;
    }

    const float* inb = in + (size_t)b * CIN_T * HW;

    #pragma unroll 1
    for (int ci = 0; ci < CIN_T; ++ci) {
        const float* pin = inb + ci * HW;
        float vals[3][10];
        #pragma unroll
        for (int r3 = 0; r3 < 3; ++r3) {
            int hh = h - 1 + r3;
            if ((unsigned)hh < (unsigned)H_) {
                const float* p = pin + hh * W_;
                float4 v0 = *(const float4*)(p + w0);
                float4 v1 = *(const float4*)(p + w0 + 4);
                vals[r3][1] = v0.x; vals[r3][2] = v0.y;
                vals[r3][3] = v0.z; vals[r3][4] = v0.w;
                vals[r3][5] = v1.x; vals[r3][6] = v1.y;
                vals[r3][7] = v1.z; vals[r3][8] = v1.w;
                vals[r3][0] = (w0 > 0)       ? p[w0 - 1] : 0.f;
                vals[r3][9] = (w0 + 8 < W_)  ? p[w0 + 8] : 0.f;
            } else {
                #pragma unroll
                for (int j = 0; j < 10; ++j) vals[r3][j] = 0.f;
            }
        }
        const float* wp = &wlds[ci * 72];
        #pragma unroll
        for (int k = 0; k < 9; ++k) {
            float4 wa = *(const float4*)(wp + k * 8);
            float4 wb = *(const float4*)(wp + k * 8 + 4);
            const int kh = k / 3, kw = k % 3;
            #pragma unroll
            for (int p = 0; p < 8; ++p) {
                float iv = vals[kh][p + kw];
                acc[0][p] += wa.x * iv;
                acc[1][p] += wa.y * iv;
                acc[2][p] += wa.z * iv;
                acc[3][p] += wa.w * iv;
                acc[4][p] += wb.x * iv;
                acc[5][p] += wb.y * iv;
                acc[6][p] += wb.z * iv;
                acc[7][p] += wb.w * iv;
            }
        }
    }

    #pragma unroll
    for (int c = 0; c < 8; ++c) {
        int co = cog * 8 + c;
        float* po = out + (size_t)(b * COUT_T + co) * HW + h * W_ + w0;
        float tmp[8];
        #pragma unroll
        for (int p = 0; p < 8; ++p) {
            float v = acc[c][p];
            if (ACT == 1) {
                v = v > 0.f ? v : 0.1f * v;
            } else if (ACT == 2) {
                if (co < 288) {
                    float e = __expf(2.f * v);          // stable tanh
                    v = 10.f * (1.f - 2.f / (e + 1.f));
                } else {
                    v = 1.f / (1.f + __expf(-v));       // sigmoid
                }
            }
            tmp[p] = v;
        }
        *(float4*)(po)     = make_float4(tmp[0], tmp[1], tmp[2], tmp[3]);
        *(float4*)(po + 4) = make_float4(tmp[4], tmp[5], tmp[6], tmp[7]);
    }
}

// ---------------------------------------------------------------------------
// transpose deform weight [o][ci=g*8+c][kh][kw] -> wt[((g*9+k)*8+c)*64 + o]
// ---------------------------------------------------------------------------
__global__ void prep_wt(const float* __restrict__ wsrc, float* __restrict__ wt) {
    int i = blockIdx.x * 256 + threadIdx.x;
    if (i >= 64 * 128 * 9) return;
    int o  = i & 63;
    int r  = i >> 6;        // ((g*9+k)*8 + c), 0..1151
    int c  = r & 7;
    int gk = r >> 3;        // g*9+k
    int k  = gk % 9;
    int g  = gk / 9;
    wt[i] = wsrc[(o * 128 + g * 8 + c) * 9 + k];
}

// ---------------------------------------------------------------------------
// deformable conv: one thread per output pixel, 64 output channels in regs.
// o4 holds post-activation conv4 output: ch 0..287 = offsets, 288..431 = mask.
// wt staged per-group in LDS (uniform broadcast reads).
// ---------------------------------------------------------------------------
__global__ __launch_bounds__(256)
void deform_kern(const float* __restrict__ x, const float* __restrict__ o4,
                 const float* __restrict__ wt, const float* __restrict__ bias,
                 float* __restrict__ out) {
    __shared__ float wlds[9 * 8 * 64];
    const int tid = threadIdx.x;
    const int px  = blockIdx.x * 256 + tid;
    const int b   = px >> 14;
    const int rem = px & (HW - 1);
    const int h   = rem >> 7;
    const int w   = rem & 127;

    float acc[64];
    #pragma unroll
    for (int o = 0; o < 64; ++o) acc[o] = bias[o];

    const float* o4b = o4 + (size_t)b * 432 * HW;
    const float* xb  = x + (size_t)b * 128 * HW;
    const int sp = h * W_ + w;

    #pragma unroll 1
    for (int g = 0; g < 16; ++g) {
        __syncthreads();
        for (int i = tid; i < 4608; i += 256) wlds[i] = wt[g * 4608 + i];
        __syncthreads();
        #pragma unroll 1
        for (int k = 0; k < 9; ++k) {
            float dy = o4b[(g * 18 + 2 * k)     * HW + sp];
            float dx = o4b[(g * 18 + 2 * k + 1) * HW + sp];
            float m  = o4b[(288 + g * 9 + k)    * HW + sp];
            float py  = (float)(h - 1 + k / 3) + dy;
            float pxx = (float)(w - 1 + k % 3) + dx;
            float y0f = floorf(py), x0f = floorf(pxx);
            float ly = py - y0f, lx = pxx - x0f;
            int y0 = (int)y0f, x0 = (int)x0f;
            int y1 = y0 + 1,  x1 = x0 + 1;
            float vy0 = ((unsigned)y0 < 128u) ? 1.f : 0.f;
            float vy1 = ((unsigned)y1 < 128u) ? 1.f : 0.f;
            float vx0 = ((unsigned)x0 < 128u) ? 1.f : 0.f;
            float vx1 = ((unsigned)x1 < 128u) ? 1.f : 0.f;
            float w00 = (1.f - ly) * (1.f - lx) * vy0 * vx0 * m;
            float w01 = (1.f - ly) * lx         * vy0 * vx1 * m;
            float w10 = ly * (1.f - lx)         * vy1 * vx0 * m;
            float w11 = ly * lx                 * vy1 * vx1 * m;
            int yc0 = min(max(y0, 0), 127), yc1 = min(max(y1, 0), 127);
            int xc0 = min(max(x0, 0), 127), xc1 = min(max(x1, 0), 127);
            int i00 = yc0 * W_ + xc0, i01 = yc0 * W_ + xc1;
            int i10 = yc1 * W_ + xc0, i11 = yc1 * W_ + xc1;
            #pragma unroll
            for (int c = 0; c < 8; ++c) {
                const float* xp = xb + (g * 8 + c) * HW;
                float s = w00 * xp[i00] + w01 * xp[i01]
                        + w10 * xp[i10] + w11 * xp[i11];
                const float* wp = &wlds[(k * 8 + c) * 64];
                #pragma unroll
                for (int o16 = 0; o16 < 16; ++o16) {
                    float4 wv = *(const float4*)(wp + o16 * 4);
                    acc[o16 * 4 + 0] += s * wv.x;
                    acc[o16 * 4 + 1] += s * wv.y;
                    acc[o16 * 4 + 2] += s * wv.z;
                    acc[o16 * 4 + 3] += s * wv.w;
                }
            }
        }
    }

    #pragma unroll
    for (int o = 0; o < 64; ++o) {
        out[(size_t)(b * 64 + o) * HW + sp] = acc[o];
    }
}

// ---------------------------------------------------------------------------
extern "C" void kernel_launch(void* const* d_in, const int* in_sizes, int n_in,
                              void* d_out, int out_size, void* d_ws, size_t ws_size,
                              hipStream_t stream) {
    const float* x  = (const float*)d_in[0];
    const float* ef = (const float*)d_in[1];
    const float* w1 = (const float*)d_in[2];
    const float* b1 = (const float*)d_in[3];
    const float* w2 = (const float*)d_in[4];
    const float* b2 = (const float*)d_in[5];
    const float* w3 = (const float*)d_in[6];
    const float* b3 = (const float*)d_in[7];
    const float* w4 = (const float*)d_in[8];
    const float* b4 = (const float*)d_in[9];
    const float* wd = (const float*)d_in[10];
    const float* bd = (const float*)d_in[11];
    float* out = (float*)d_out;

    char* ws = (char*)d_ws;
    float* tA = (float*)(ws);                                   // 16 MB
    float* tB = (float*)(ws + 16777216);                        // 16 MB
    float* o4 = (float*)(ws + 2 * 16777216);                    // 113.25 MB
    float* wt = (float*)(ws + 2 * 16777216 + 113246208);        // 0.29 MB

    prep_wt<<<288, 256, 0, stream>>>(wd, wt);
    conv3x3_kern<192, 64, 1><<<dim3(32, 8),  256, 0, stream>>>(ef, w1, b1, tA);
    conv3x3_kern< 64, 64, 1><<<dim3(32, 8),  256, 0, stream>>>(tA, w2, b2, tB);
    conv3x3_kern< 64, 64, 1><<<dim3(32, 8),  256, 0, stream>>>(tB, w3, b3, tA);
    conv3x3_kern< 64, 432, 2><<<dim3(32, 54), 256, 0, stream>>>(tA, w4, b4, o4);
    deform_kern<<<256, 256, 0, stream>>>(x, o4, wt, bd, out);
}

// Round 2
// 1398.251 us; speedup vs baseline: 1.1447x; 1.1447x over previous
//
#include <hip/hip_runtime.h>
#include <cstdint>

#define H_ 128
#define W_ 128
#define HW 16384

typedef short bf16x8 __attribute__((ext_vector_type(8)));
typedef short short4v __attribute__((ext_vector_type(4)));
typedef float f32x4 __attribute__((ext_vector_type(4)));

__device__ inline short f2bf(float f) {
    unsigned u = __builtin_bit_cast(unsigned, f);
    u = (u + 0x7fffu + ((u >> 16) & 1u)) >> 16;
    return (short)u;
}

// ---------------------------------------------------------------------------
// conv3x3, NCHW, pad 1 (unchanged from R1). Per block: 8 output channels,
// spatial tile 32x64. Per thread: 8 px x 8 co.
// ACT: 1 = leaky_relu(0.1), 2 = conv4 epilogue (10*tanh / sigmoid)
// ---------------------------------------------------------------------------
template<int CIN_T, int COUT_T, int ACT>
__global__ __launch_bounds__(256)
void conv3x3_kern(const float* __restrict__ in, const float* __restrict__ wsrc,
                  const float* __restrict__ bias, float* __restrict__ out) {
    __shared__ float wlds[CIN_T * 9 * 8];
    const int tid = threadIdx.x;
    const int bx  = blockIdx.x;
    const int cog = blockIdx.y;
    const int b   = bx >> 3;
    const int t   = bx & 7;
    const int th  = (t >> 1) * 32;
    const int tw  = (t & 1) * 64;

    for (int i = tid; i < CIN_T * 9 * 8; i += 256) {
        int co8 = i / (CIN_T * 9);
        int r   = i - co8 * (CIN_T * 9);
        wlds[r * 8 + co8] = wsrc[(cog * 8 + co8) * (CIN_T * 9) + r];
    }
    __syncthreads();

    const int rrow = tid >> 3;
    const int cg   = tid & 7;
    const int h    = th + rrow;
    const int w0   = tw + cg * 8;

    float acc[8][8];
    #pragma unroll
    for (int c = 0; c < 8; ++c) {
        float bv = bias[cog * 8 + c];
        #pragma unroll
        for (int p = 0; p < 8; ++p) acc[c][p] = bv;
    }

    const float* inb = in + (size_t)b * CIN_T * HW;

    #pragma unroll 1
    for (int ci = 0; ci < CIN_T; ++ci) {
        const float* pin = inb + ci * HW;
        float vals[3][10];
        #pragma unroll
        for (int r3 = 0; r3 < 3; ++r3) {
            int hh = h - 1 + r3;
            if ((unsigned)hh < (unsigned)H_) {
                const float* p = pin + hh * W_;
                float4 v0 = *(const float4*)(p + w0);
                float4 v1 = *(const float4*)(p + w0 + 4);
                vals[r3][1] = v0.x; vals[r3][2] = v0.y;
                vals[r3][3] = v0.z; vals[r3][4] = v0.w;
                vals[r3][5] = v1.x; vals[r3][6] = v1.y;
                vals[r3][7] = v1.z; vals[r3][8] = v1.w;
                vals[r3][0] = (w0 > 0)       ? p[w0 - 1] : 0.f;
                vals[r3][9] = (w0 + 8 < W_)  ? p[w0 + 8] : 0.f;
            } else {
                #pragma unroll
                for (int j = 0; j < 10; ++j) vals[r3][j] = 0.f;
            }
        }
        const float* wp = &wlds[ci * 72];
        #pragma unroll
        for (int k = 0; k < 9; ++k) {
            float4 wa = *(const float4*)(wp + k * 8);
            float4 wb = *(const float4*)(wp + k * 8 + 4);
            const int kh = k / 3, kw = k % 3;
            #pragma unroll
            for (int p = 0; p < 8; ++p) {
                float iv = vals[kh][p + kw];
                acc[0][p] += wa.x * iv;
                acc[1][p] += wa.y * iv;
                acc[2][p] += wa.z * iv;
                acc[3][p] += wa.w * iv;
                acc[4][p] += wb.x * iv;
                acc[5][p] += wb.y * iv;
                acc[6][p] += wb.z * iv;
                acc[7][p] += wb.w * iv;
            }
        }
    }

    #pragma unroll
    for (int c = 0; c < 8; ++c) {
        int co = cog * 8 + c;
        float* po = out + (size_t)(b * COUT_T + co) * HW + h * W_ + w0;
        float tmp[8];
        #pragma unroll
        for (int p = 0; p < 8; ++p) {
            float v = acc[c][p];
            if (ACT == 1) {
                v = v > 0.f ? v : 0.1f * v;
            } else if (ACT == 2) {
                if (co < 288) {
                    float e = __expf(2.f * v);
                    v = 10.f * (1.f - 2.f / (e + 1.f));
                } else {
                    v = 1.f / (1.f + __expf(-v));
                }
            }
            tmp[p] = v;
        }
        *(float4*)(po)     = make_float4(tmp[0], tmp[1], tmp[2], tmp[3]);
        *(float4*)(po + 4) = make_float4(tmp[4], tmp[5], tmp[6], tmp[7]);
    }
}

// ---------------------------------------------------------------------------
// deform weight -> bf16 Wp[g][o][kc96], kc = k*8+c, kc>=72 zero-padded.
// ---------------------------------------------------------------------------
__global__ void prep_wp(const float* __restrict__ wsrc, short* __restrict__ wp) {
    int i = blockIdx.x * 256 + threadIdx.x;   // (g*64+o)*96 + kc
    if (i >= 16 * 64 * 96) return;
    int kc = i % 96;
    int go = i / 96;
    int o  = go & 63;
    int g  = go >> 6;
    float v = 0.f;
    if (kc < 72) {
        int k = kc >> 3, c = kc & 7;
        v = wsrc[(o * 128 + g * 8 + c) * 9 + k];
    }
    wp[i] = f2bf(v);
}

// ---------------------------------------------------------------------------
// Fused deformable conv via MFMA. Block = one image row (b, h): 128 px.
// Per g: 256 threads build V[px=128][kc=96 bf16] in LDS (bilinear gather,
// mask folded), XOR-chunk swizzle (16B chunk index ^= row&7) -> only 2-way
// bank conflicts (free). Then 4 waves: wave w = o-tile w*16..w*16+15,
// A-frags from global Wp (3 K-steps), 8 n-tiles of 16 px, fp32 acc.
// ---------------------------------------------------------------------------
__global__ __launch_bounds__(256)
void deform_mfma(const float* __restrict__ x, const float* __restrict__ o4,
                 const short* __restrict__ wp, const float* __restrict__ bias,
                 float* __restrict__ out) {
    __shared__ char vlds[128 * 256];   // 32 KB: 128 rows x 16 chunks x 16 B
    const int tid  = threadIdx.x;
    const int b    = blockIdx.x >> 7;
    const int h    = blockIdx.x & 127;
    const int wv   = tid >> 6;         // wave id = m-tile
    const int lane = tid & 63;
    const int quad = lane >> 4;
    const int l16  = lane & 15;

    // V-build role: one pixel per thread-pair, split channels 4+4
    const int wcol  = tid & 127;       // w coordinate == V row
    const int chalf = tid >> 7;        // 0: c0..3, 1: c4..7

    // zero-init V (chunks >= 9 stay zero forever = K padding)
    {
        short4v z = (short4v){0, 0, 0, 0};
        for (int i = tid; i < 4096; i += 256) ((short4v*)vlds)[i] = z;
    }

    const float* o4b = o4 + (size_t)b * 432 * HW + h * W_ + wcol;
    const float* xb  = x + (size_t)b * 128 * HW;

    f32x4 acc[8];
    #pragma unroll
    for (int nt = 0; nt < 8; ++nt) acc[nt] = (f32x4){0.f, 0.f, 0.f, 0.f};

    #pragma unroll 1
    for (int g = 0; g < 16; ++g) {
        __syncthreads();               // prior MFMA reads done
        // ---- build V tile ----
        #pragma unroll 1
        for (int k = 0; k < 9; ++k) {
            float dy = o4b[(g * 18 + 2 * k) * HW];
            float dx = o4b[(g * 18 + 2 * k + 1) * HW];
            float m  = o4b[(288 + g * 9 + k) * HW];
            float py  = (float)(h - 1 + k / 3) + dy;
            float pxf = (float)(wcol - 1 + k % 3) + dx;
            float y0f = floorf(py), x0f = floorf(pxf);
            float ly = py - y0f, lx = pxf - x0f;
            int y0 = (int)y0f, x0 = (int)x0f;
            int y1 = y0 + 1,  x1 = x0 + 1;
            float vy0 = ((unsigned)y0 < 128u) ? 1.f : 0.f;
            float vy1 = ((unsigned)y1 < 128u) ? 1.f : 0.f;
            float vx0 = ((unsigned)x0 < 128u) ? 1.f : 0.f;
            float vx1 = ((unsigned)x1 < 128u) ? 1.f : 0.f;
            float w00 = (1.f - ly) * (1.f - lx) * vy0 * vx0 * m;
            float w01 = (1.f - ly) * lx         * vy0 * vx1 * m;
            float w10 = ly * (1.f - lx)         * vy1 * vx0 * m;
            float w11 = ly * lx                 * vy1 * vx1 * m;
            int yc0 = min(max(y0, 0), 127), yc1 = min(max(y1, 0), 127);
            int xc0 = min(max(x0, 0), 127), xc1 = min(max(x1, 0), 127);
            int i00 = yc0 * W_ + xc0, i01 = yc0 * W_ + xc1;
            int i10 = yc1 * W_ + xc0, i11 = yc1 * W_ + xc1;
            short4v vv;
            #pragma unroll
            for (int c = 0; c < 4; ++c) {
                const float* xp = xb + (g * 8 + chalf * 4 + c) * HW;
                float s = w00 * xp[i00] + w01 * xp[i01]
                        + w10 * xp[i10] + w11 * xp[i11];
                vv[c] = f2bf(s);
            }
            int chunk = k ^ (wcol & 7);
            *(short4v*)(vlds + wcol * 256 + chunk * 16 + chalf * 8) = vv;
        }
        __syncthreads();               // V visible
        // ---- MFMA ----
        bf16x8 aF[3];
        const short* wg = wp + ((size_t)(g * 64 + wv * 16 + l16)) * 96 + quad * 8;
        #pragma unroll
        for (int s = 0; s < 3; ++s) aF[s] = *(const bf16x8*)(wg + s * 32);
        #pragma unroll
        for (int nt = 0; nt < 8; ++nt) {
            int rb = (nt * 16 + l16) * 256;
            int sw = (nt * 16 + l16) & 7;
            #pragma unroll
            for (int s = 0; s < 3; ++s) {
                bf16x8 bF = *(const bf16x8*)(vlds + rb + (((s << 2) + quad) ^ sw) * 16);
                acc[nt] = __builtin_amdgcn_mfma_f32_16x16x32_bf16(aF[s], bF, acc[nt], 0, 0, 0);
            }
        }
    }

    // ---- epilogue: D col = px (lane&15), row = o (quad*4 + r) ----
    const int obase = wv * 16 + quad * 4;
    #pragma unroll
    for (int r = 0; r < 4; ++r) {
        const float bv = bias[obase + r];
        float* po = out + ((size_t)(b * 64 + obase + r)) * HW + h * W_ + l16;
        #pragma unroll
        for (int nt = 0; nt < 8; ++nt) {
            po[nt * 16] = acc[nt][r] + bv;
        }
    }
}

// ---------------------------------------------------------------------------
extern "C" void kernel_launch(void* const* d_in, const int* in_sizes, int n_in,
                              void* d_out, int out_size, void* d_ws, size_t ws_size,
                              hipStream_t stream) {
    const float* x  = (const float*)d_in[0];
    const float* ef = (const float*)d_in[1];
    const float* w1 = (const float*)d_in[2];
    const float* b1 = (const float*)d_in[3];
    const float* w2 = (const float*)d_in[4];
    const float* b2 = (const float*)d_in[5];
    const float* w3 = (const float*)d_in[6];
    const float* b3 = (const float*)d_in[7];
    const float* w4 = (const float*)d_in[8];
    const float* b4 = (const float*)d_in[9];
    const float* wd = (const float*)d_in[10];
    const float* bd = (const float*)d_in[11];
    float* out = (float*)d_out;

    char* ws = (char*)d_ws;
    float* tA = (float*)(ws);                                   // 16 MB
    float* tB = (float*)(ws + 16777216);                        // 16 MB
    float* o4 = (float*)(ws + 2 * 16777216);                    // 113.25 MB
    short* wpd = (short*)(ws + 2 * 16777216 + 113246208);       // 192 KB bf16

    prep_wp<<<384, 256, 0, stream>>>(wd, wpd);
    conv3x3_kern<192, 64, 1><<<dim3(32, 8),  256, 0, stream>>>(ef, w1, b1, tA);
    conv3x3_kern< 64, 64, 1><<<dim3(32, 8),  256, 0, stream>>>(tA, w2, b2, tB);
    conv3x3_kern< 64, 64, 1><<<dim3(32, 8),  256, 0, stream>>>(tB, w3, b3, tA);
    conv3x3_kern< 64, 432, 2><<<dim3(32, 54), 256, 0, stream>>>(tA, w4, b4, o4);
    deform_mfma<<<512, 256, 0, stream>>>(x, o4, wpd, bd, out);
}

// Round 4
// 571.878 us; speedup vs baseline: 2.7987x; 2.4450x over previous
//
#include <hip/hip_runtime.h>
#include <cstdint>

#define H_ 128
#define W_ 128
#define HW 16384

typedef _Float16 f16x8 __attribute__((ext_vector_type(8)));
typedef _Float16 f16x4 __attribute__((ext_vector_type(4)));
typedef float f32x4 __attribute__((ext_vector_type(4)));

// ---------------------------------------------------------------------------
// NCHW fp32 -> NHWC fp16 transpose for extra_feat (192 ch). Block = 1 row.
// ---------------------------------------------------------------------------
__global__ __launch_bounds__(256)
void transpose_ef(const float* __restrict__ ef, _Float16* __restrict__ out) {
    __shared__ __align__(16) _Float16 t[128 * 200];  // px-major, ch padded
    const int tid = threadIdx.x;
    const int b = blockIdx.x >> 7;
    const int h = blockIdx.x & 127;
    for (int i = tid; i < 192 * 128; i += 256) {
        int c = i >> 7, w = i & 127;
        t[w * 200 + c] = (_Float16)ef[((size_t)(b * 192 + c) * 128 + h) * 128 + w];
    }
    __syncthreads();
    _Float16* ob = out + ((size_t)(b * 128 + h) * 128) * 192;
    for (int i = tid; i < 128 * 24; i += 256) {
        int px = i / 24, c8 = i % 24;
        *(f16x8*)(ob + px * 192 + c8 * 8) = *(const f16x8*)(t + px * 200 + c8 * 8);
    }
}

// ---------------------------------------------------------------------------
// conv weight (COUT,CIN,3,3) fp32 -> A layout fp16:
// Ap[kb][co][j], k = kb*8+j = (kh*3+kw)*CIN + ci ; co padded to COpad (zeros)
// ---------------------------------------------------------------------------
__global__ void prep_convA(const float* __restrict__ w, _Float16* __restrict__ Ap,
                           int CIN, int COUT, int COpad) {
    int i = blockIdx.x * 256 + threadIdx.x;
    int total = 9 * CIN * COpad;
    if (i >= total) return;
    int kb = i / (COpad * 8);
    int rem = i - kb * (COpad * 8);
    int co = rem >> 3, j = rem & 7;
    int k = kb * 8 + j;
    int s = k / CIN;
    int ci = k - s * CIN;
    int kh = s / 3, kw = s % 3;
    float v = (co < COUT) ? w[((size_t)co * CIN + ci) * 9 + kh * 3 + kw] : 0.f;
    Ap[i] = (_Float16)v;
}

// ---------------------------------------------------------------------------
// MFMA implicit-GEMM 3x3 conv, pad 1. Input NHWC fp16. Block = 1 output row
// (128 px) x 64 co (blockIdx.y co-group). 4 waves = 2(m:32co) x 2(n:64px).
// LDS: im2col rows staged as [kh_l][w'=0..129][c8 chunks], 16B-chunk XOR
// swizzle by (w'&7) -> 2-way conflicts only (free).
// ACT 1 = lrelu(0.1), out NHWC fp16 (COUT=64). ACT 2 = conv4 epilogue
// (10*tanh / sigmoid), out NCHW fp16 (432 ch).
// ---------------------------------------------------------------------------
template<int CIN_T, int COpad_T, int ACT>
__global__ __launch_bounds__(256)
void conv_mfma(const _Float16* __restrict__ in, const _Float16* __restrict__ Ap,
               const float* __restrict__ bias, void* __restrict__ outp) {
    constexpr int NKH = (CIN_T == 64) ? 3 : 1;   // kh rows per stage
    constexpr int NST = 3 / NKH;                 // stages
    constexpr int CPC = CIN_T / 8;               // 16B chunks per pixel
    constexpr int TC  = NKH * 130 * CPC;         // chunks per stage (=3120)
    __shared__ __align__(16) _Float16 lds[TC * 8];  // 49920 B

    const int tid  = threadIdx.x;
    const int b    = blockIdx.x >> 7;
    const int h    = blockIdx.x & 127;
    const int cogB = blockIdx.y * 64;
    const int wv_m = tid >> 7;
    const int wv_n = (tid >> 6) & 1;
    const int lane = tid & 63;
    const int quad = lane >> 4;
    const int l16  = lane & 15;

    f32x4 acc[2][4];
    #pragma unroll
    for (int mt = 0; mt < 2; ++mt)
        #pragma unroll
        for (int nt = 0; nt < 4; ++nt) acc[mt][nt] = (f32x4){0.f, 0.f, 0.f, 0.f};

    const _Float16* inb = in + (size_t)b * (HW * CIN_T);

    #pragma unroll 1
    for (int s = 0; s < NST; ++s) {
        __syncthreads();
        // ---- stage ----
        for (int i = tid; i < TC; i += 256) {
            int kh_l = i / (130 * CPC);
            int r2   = i - kh_l * (130 * CPC);
            int wp_  = r2 / CPC;
            int c8   = r2 - wp_ * CPC;
            int kh   = s * NKH + kh_l;
            int hh   = h - 1 + kh;
            int w    = wp_ - 1;
            f16x8 v = (f16x8){0, 0, 0, 0, 0, 0, 0, 0};
            if ((unsigned)hh < 128u && (unsigned)w < 128u)
                v = *(const f16x8*)(inb + (hh * 128 + w) * CIN_T + c8 * 8);
            int slot = (c8 & ~7) | ((c8 & 7) ^ (wp_ & 7));
            ((f16x8*)lds)[(kh_l * 130 + wp_) * CPC + slot] = v;
        }
        __syncthreads();
        // ---- MFMA over this stage's K slice ----
        #pragma unroll
        for (int kh_l = 0; kh_l < NKH; ++kh_l) {
            const int kh = s * NKH + kh_l;
            #pragma unroll
            for (int kwi = 0; kwi < 3; ++kwi) {
                #pragma unroll
                for (int ci32 = 0; ci32 < CIN_T / 32; ++ci32) {
                    const int kb0 = (kh * 3 + kwi) * CPC + ci32 * 4;
                    f16x8 aF[2];
                    #pragma unroll
                    for (int mt = 0; mt < 2; ++mt) {
                        int co_m = cogB + wv_m * 32 + mt * 16 + l16;
                        aF[mt] = *(const f16x8*)(Ap + ((size_t)(kb0 + quad) * COpad_T + co_m) * 8);
                    }
                    const int c8v = ci32 * 4 + quad;
                    #pragma unroll
                    for (int nt = 0; nt < 4; ++nt) {
                        int n  = wv_n * 64 + nt * 16 + l16;
                        int wq = n + kwi;
                        int slot = (c8v & ~7) | ((c8v & 7) ^ (wq & 7));
                        f16x8 bF = ((const f16x8*)lds)[(kh_l * 130 + wq) * CPC + slot];
                        acc[0][nt] = __builtin_amdgcn_mfma_f32_16x16x32_f16(aF[0], bF, acc[0][nt], 0, 0, 0);
                        acc[1][nt] = __builtin_amdgcn_mfma_f32_16x16x32_f16(aF[1], bF, acc[1][nt], 0, 0, 0);
                    }
                }
            }
        }
    }

    // ---- epilogue: D lane: col n = l16 (px), row m = quad*4 + r (co) ----
    if (ACT == 1) {
        _Float16* ob = (_Float16*)outp + ((size_t)(b * 128 + h) * 128) * 64;
        #pragma unroll
        for (int mt = 0; mt < 2; ++mt) {
            int co_b = wv_m * 32 + mt * 16 + quad * 4;
            #pragma unroll
            for (int nt = 0; nt < 4; ++nt) {
                int px = wv_n * 64 + nt * 16 + l16;
                f16x4 sv;
                #pragma unroll
                for (int r = 0; r < 4; ++r) {
                    float v = acc[mt][nt][r] + bias[co_b + r];
                    v = v > 0.f ? v : 0.1f * v;
                    sv[r] = (_Float16)v;
                }
                *(f16x4*)(ob + px * 64 + co_b) = sv;
            }
        }
    } else {
        _Float16* ob = (_Float16*)outp + (size_t)b * 432 * HW + h * 128;
        #pragma unroll
        for (int mt = 0; mt < 2; ++mt) {
            #pragma unroll
            for (int r = 0; r < 4; ++r) {
                int co = cogB + wv_m * 32 + mt * 16 + quad * 4 + r;
                if (co < 432) {
                    float bv = bias[co];
                    #pragma unroll
                    for (int nt = 0; nt < 4; ++nt) {
                        int px = wv_n * 64 + nt * 16 + l16;
                        float v = acc[mt][nt][r] + bv;
                        if (co < 288) {
                            float e = __expf(2.f * v);
                            v = 10.f * (1.f - 2.f / (e + 1.f));
                        } else {
                            v = 1.f / (1.f + __expf(-v));
                        }
                        ob[(size_t)co * HW + px] = (_Float16)v;
                    }
                }
            }
        }
    }
}

// ---------------------------------------------------------------------------
// deform weight -> fp16 Wp[g][o][kc96], kc = k*8+c, kc>=72 zero-padded.
// ---------------------------------------------------------------------------
__global__ void prep_wp(const float* __restrict__ wsrc, _Float16* __restrict__ wp) {
    int i = blockIdx.x * 256 + threadIdx.x;
    if (i >= 16 * 64 * 96) return;
    int kc = i % 96;
    int go = i / 96;
    int o  = go & 63;
    int g  = go >> 6;
    float v = 0.f;
    if (kc < 72) {
        int k = kc >> 3, c = kc & 7;
        v = wsrc[(o * 128 + g * 8 + c) * 9 + k];
    }
    wp[i] = (_Float16)v;
}

// ---------------------------------------------------------------------------
// Fused deformable conv via MFMA (fp16 V tile / weights, fp32 accum).
// ---------------------------------------------------------------------------
__global__ __launch_bounds__(256)
void deform_mfma(const float* __restrict__ x, const _Float16* __restrict__ o4,
                 const _Float16* __restrict__ wp, const float* __restrict__ bias,
                 float* __restrict__ out) {
    __shared__ char vlds[128 * 256];   // 32 KB: 128 rows x 16 chunks x 16 B
    const int tid  = threadIdx.x;
    const int b    = blockIdx.x >> 7;
    const int h    = blockIdx.x & 127;
    const int wv   = tid >> 6;
    const int lane = tid & 63;
    const int quad = lane >> 4;
    const int l16  = lane & 15;

    const int wcol  = tid & 127;
    const int chalf = tid >> 7;

    {
        f16x4 z = (f16x4){0, 0, 0, 0};
        for (int i = tid; i < 4096; i += 256) ((f16x4*)vlds)[i] = z;
    }

    const _Float16* o4b = o4 + (size_t)b * 432 * HW + h * W_ + wcol;
    const float* xb  = x + (size_t)b * 128 * HW;

    f32x4 acc[8];
    #pragma unroll
    for (int nt = 0; nt < 8; ++nt) acc[nt] = (f32x4){0.f, 0.f, 0.f, 0.f};

    #pragma unroll 1
    for (int g = 0; g < 16; ++g) {
        __syncthreads();
        #pragma unroll 1
        for (int k = 0; k < 9; ++k) {
            float dy = (float)o4b[(g * 18 + 2 * k) * HW];
            float dx = (float)o4b[(g * 18 + 2 * k + 1) * HW];
            float m  = (float)o4b[(288 + g * 9 + k) * HW];
            float py  = (float)(h - 1 + k / 3) + dy;
            float pxf = (float)(wcol - 1 + k % 3) + dx;
            float y0f = floorf(py), x0f = floorf(pxf);
            float ly = py - y0f, lx = pxf - x0f;
            int y0 = (int)y0f, x0 = (int)x0f;
            int y1 = y0 + 1,  x1 = x0 + 1;
            float vy0 = ((unsigned)y0 < 128u) ? 1.f : 0.f;
            float vy1 = ((unsigned)y1 < 128u) ? 1.f : 0.f;
            float vx0 = ((unsigned)x0 < 128u) ? 1.f : 0.f;
            float vx1 = ((unsigned)x1 < 128u) ? 1.f : 0.f;
            float w00 = (1.f - ly) * (1.f - lx) * vy0 * vx0 * m;
            float w01 = (1.f - ly) * lx         * vy0 * vx1 * m;
            float w10 = ly * (1.f - lx)         * vy1 * vx0 * m;
            float w11 = ly * lx                 * vy1 * vx1 * m;
            int yc0 = min(max(y0, 0), 127), yc1 = min(max(y1, 0), 127);
            int xc0 = min(max(x0, 0), 127), xc1 = min(max(x1, 0), 127);
            int i00 = yc0 * W_ + xc0, i01 = yc0 * W_ + xc1;
            int i10 = yc1 * W_ + xc0, i11 = yc1 * W_ + xc1;
            f16x4 vv;
            #pragma unroll
            for (int c = 0; c < 4; ++c) {
                const float* xp = xb + (g * 8 + chalf * 4 + c) * HW;
                float s = w00 * xp[i00] + w01 * xp[i01]
                        + w10 * xp[i10] + w11 * xp[i11];
                vv[c] = (_Float16)s;
            }
            int chunk = k ^ (wcol & 7);
            *(f16x4*)(vlds + wcol * 256 + chunk * 16 + chalf * 8) = vv;
        }
        __syncthreads();
        f16x8 aF[3];
        const _Float16* wg = wp + ((size_t)(g * 64 + wv * 16 + l16)) * 96 + quad * 8;
        #pragma unroll
        for (int s = 0; s < 3; ++s) aF[s] = *(const f16x8*)(wg + s * 32);
        #pragma unroll
        for (int nt = 0; nt < 8; ++nt) {
            int rb = (nt * 16 + l16) * 256;
            int sw = (nt * 16 + l16) & 7;
            #pragma unroll
            for (int s = 0; s < 3; ++s) {
                f16x8 bF = *(const f16x8*)(vlds + rb + (((s << 2) + quad) ^ sw) * 16);
                acc[nt] = __builtin_amdgcn_mfma_f32_16x16x32_f16(aF[s], bF, acc[nt], 0, 0, 0);
            }
        }
    }

    const int obase = wv * 16 + quad * 4;
    #pragma unroll
    for (int r = 0; r < 4; ++r) {
        const float bv = bias[obase + r];
        float* po = out + ((size_t)(b * 64 + obase + r)) * HW + h * W_ + l16;
        #pragma unroll
        for (int nt = 0; nt < 8; ++nt) {
            po[nt * 16] = acc[nt][r] + bv;
        }
    }
}

// ---------------------------------------------------------------------------
extern "C" void kernel_launch(void* const* d_in, const int* in_sizes, int n_in,
                              void* d_out, int out_size, void* d_ws, size_t ws_size,
                              hipStream_t stream) {
    const float* x  = (const float*)d_in[0];
    const float* ef = (const float*)d_in[1];
    const float* w1 = (const float*)d_in[2];
    const float* b1 = (const float*)d_in[3];
    const float* w2 = (const float*)d_in[4];
    const float* b2 = (const float*)d_in[5];
    const float* w3 = (const float*)d_in[6];
    const float* b3 = (const float*)d_in[7];
    const float* w4 = (const float*)d_in[8];
    const float* b4 = (const float*)d_in[9];
    const float* wd = (const float*)d_in[10];
    const float* bd = (const float*)d_in[11];
    float* out = (float*)d_out;

    char* ws = (char*)d_ws;
    _Float16* ef_t = (_Float16*)(ws);                     // 25,165,824 B
    _Float16* tA   = (_Float16*)(ws + 25165824);          //  8,388,608 B
    _Float16* tB   = (_Float16*)(ws + 33554432);          //  8,388,608 B
    _Float16* o4h  = (_Float16*)(ws + 41943040);          // 56,623,104 B
    _Float16* wpd  = (_Float16*)(ws + 98566144);          //    196,608 B
    _Float16* A1   = (_Float16*)(ws + 98762752);          //    221,184 B
    _Float16* A2   = (_Float16*)(ws + 98983936);          //     73,728 B
    _Float16* A3   = (_Float16*)(ws + 99057664);          //     73,728 B
    _Float16* A4   = (_Float16*)(ws + 99131392);          //    516,096 B

    prep_wp<<<384, 256, 0, stream>>>(wd, wpd);
    prep_convA<<<432, 256, 0, stream>>>(w1, A1, 192, 64, 64);
    prep_convA<<<144, 256, 0, stream>>>(w2, A2, 64, 64, 64);
    prep_convA<<<144, 256, 0, stream>>>(w3, A3, 64, 64, 64);
    prep_convA<<<1008, 256, 0, stream>>>(w4, A4, 64, 432, 448);
    transpose_ef<<<512, 256, 0, stream>>>(ef, ef_t);

    conv_mfma<192, 64, 1><<<dim3(512, 1), 256, 0, stream>>>(ef_t, A1, b1, tA);
    conv_mfma< 64, 64, 1><<<dim3(512, 1), 256, 0, stream>>>(tA, A2, b2, tB);
    conv_mfma< 64, 64, 1><<<dim3(512, 1), 256, 0, stream>>>(tB, A3, b3, tA);
    conv_mfma< 64, 448, 2><<<dim3(512, 7), 256, 0, stream>>>(tA, A4, b4, o4h);

    deform_mfma<<<512, 256, 0, stream>>>(x, o4h, wpd, bd, out);
}

// Round 5
// 398.413 us; speedup vs baseline: 4.0173x; 1.4354x over previous
//
#include <hip/hip_runtime.h>
#include <cstdint>

#define H_ 128
#define W_ 128
#define HW 16384

typedef _Float16 f16x8 __attribute__((ext_vector_type(8)));
typedef _Float16 f16x4 __attribute__((ext_vector_type(4)));
typedef float f32x4 __attribute__((ext_vector_type(4)));

// ---------------------------------------------------------------------------
// NCHW fp32 -> NHWC fp16 transpose for extra_feat (192 ch). Block = 1 row.
// ---------------------------------------------------------------------------
__global__ __launch_bounds__(256)
void transpose_ef(const float* __restrict__ ef, _Float16* __restrict__ out) {
    __shared__ __align__(16) _Float16 t[128 * 200];  // px-major, ch padded
    const int tid = threadIdx.x;
    const int b = blockIdx.x >> 7;
    const int h = blockIdx.x & 127;
    for (int i = tid; i < 192 * 128; i += 256) {
        int c = i >> 7, w = i & 127;
        t[w * 200 + c] = (_Float16)ef[((size_t)(b * 192 + c) * 128 + h) * 128 + w];
    }
    __syncthreads();
    _Float16* ob = out + ((size_t)(b * 128 + h) * 128) * 192;
    for (int i = tid; i < 128 * 24; i += 256) {
        int px = i / 24, c8 = i % 24;
        *(f16x8*)(ob + px * 192 + c8 * 8) = *(const f16x8*)(t + px * 200 + c8 * 8);
    }
}

// ---------------------------------------------------------------------------
// x NCHW fp32 -> xt[b][g][px][c8] fp16 (16B chunk per (px,g)).
// ---------------------------------------------------------------------------
__global__ __launch_bounds__(256)
void transpose_x(const float* __restrict__ x, _Float16* __restrict__ xt) {
    int i = blockIdx.x * 256 + threadIdx.x;   // over 4*16*16384
    int px = i & 16383;
    int g  = (i >> 14) & 15;
    int b  = i >> 18;
    const float* xp = x + ((size_t)(b * 128 + g * 8) * HW) + px;
    f16x8 v;
    #pragma unroll
    for (int c = 0; c < 8; ++c) v[c] = (_Float16)xp[c * HW];
    *(f16x8*)(xt + (size_t)i * 8) = v;
}

// ---------------------------------------------------------------------------
// conv weight (COUT,CIN,3,3) fp32 -> A layout fp16:
// Ap[kb][co][j], k = kb*8+j = (kh*3+kw)*CIN + ci ; co padded to COpad (zeros)
// ---------------------------------------------------------------------------
__global__ void prep_convA(const float* __restrict__ w, _Float16* __restrict__ Ap,
                           int CIN, int COUT, int COpad) {
    int i = blockIdx.x * 256 + threadIdx.x;
    int total = 9 * CIN * COpad;
    if (i >= total) return;
    int kb = i / (COpad * 8);
    int rem = i - kb * (COpad * 8);
    int co = rem >> 3, j = rem & 7;
    int k = kb * 8 + j;
    int s = k / CIN;
    int ci = k - s * CIN;
    int kh = s / 3, kw = s % 3;
    float v = (co < COUT) ? w[((size_t)co * CIN + ci) * 9 + kh * 3 + kw] : 0.f;
    Ap[i] = (_Float16)v;
}

// ---------------------------------------------------------------------------
// MFMA implicit-GEMM 3x3 conv, pad 1 (unchanged from R4).
// ---------------------------------------------------------------------------
template<int CIN_T, int COpad_T, int ACT>
__global__ __launch_bounds__(256)
void conv_mfma(const _Float16* __restrict__ in, const _Float16* __restrict__ Ap,
               const float* __restrict__ bias, void* __restrict__ outp) {
    constexpr int NKH = (CIN_T == 64) ? 3 : 1;
    constexpr int NST = 3 / NKH;
    constexpr int CPC = CIN_T / 8;
    constexpr int TC  = NKH * 130 * CPC;
    __shared__ __align__(16) _Float16 lds[TC * 8];

    const int tid  = threadIdx.x;
    const int b    = blockIdx.x >> 7;
    const int h    = blockIdx.x & 127;
    const int cogB = blockIdx.y * 64;
    const int wv_m = tid >> 7;
    const int wv_n = (tid >> 6) & 1;
    const int lane = tid & 63;
    const int quad = lane >> 4;
    const int l16  = lane & 15;

    f32x4 acc[2][4];
    #pragma unroll
    for (int mt = 0; mt < 2; ++mt)
        #pragma unroll
        for (int nt = 0; nt < 4; ++nt) acc[mt][nt] = (f32x4){0.f, 0.f, 0.f, 0.f};

    const _Float16* inb = in + (size_t)b * (HW * CIN_T);

    #pragma unroll 1
    for (int s = 0; s < NST; ++s) {
        __syncthreads();
        for (int i = tid; i < TC; i += 256) {
            int kh_l = i / (130 * CPC);
            int r2   = i - kh_l * (130 * CPC);
            int wp_  = r2 / CPC;
            int c8   = r2 - wp_ * CPC;
            int kh   = s * NKH + kh_l;
            int hh   = h - 1 + kh;
            int w    = wp_ - 1;
            f16x8 v = (f16x8){0, 0, 0, 0, 0, 0, 0, 0};
            if ((unsigned)hh < 128u && (unsigned)w < 128u)
                v = *(const f16x8*)(inb + (hh * 128 + w) * CIN_T + c8 * 8);
            int slot = (c8 & ~7) | ((c8 & 7) ^ (wp_ & 7));
            ((f16x8*)lds)[(kh_l * 130 + wp_) * CPC + slot] = v;
        }
        __syncthreads();
        #pragma unroll
        for (int kh_l = 0; kh_l < NKH; ++kh_l) {
            const int kh = s * NKH + kh_l;
            #pragma unroll
            for (int kwi = 0; kwi < 3; ++kwi) {
                #pragma unroll
                for (int ci32 = 0; ci32 < CIN_T / 32; ++ci32) {
                    const int kb0 = (kh * 3 + kwi) * CPC + ci32 * 4;
                    f16x8 aF[2];
                    #pragma unroll
                    for (int mt = 0; mt < 2; ++mt) {
                        int co_m = cogB + wv_m * 32 + mt * 16 + l16;
                        aF[mt] = *(const f16x8*)(Ap + ((size_t)(kb0 + quad) * COpad_T + co_m) * 8);
                    }
                    const int c8v = ci32 * 4 + quad;
                    #pragma unroll
                    for (int nt = 0; nt < 4; ++nt) {
                        int n  = wv_n * 64 + nt * 16 + l16;
                        int wq = n + kwi;
                        int slot = (c8v & ~7) | ((c8v & 7) ^ (wq & 7));
                        f16x8 bF = ((const f16x8*)lds)[(kh_l * 130 + wq) * CPC + slot];
                        acc[0][nt] = __builtin_amdgcn_mfma_f32_16x16x32_f16(aF[0], bF, acc[0][nt], 0, 0, 0);
                        acc[1][nt] = __builtin_amdgcn_mfma_f32_16x16x32_f16(aF[1], bF, acc[1][nt], 0, 0, 0);
                    }
                }
            }
        }
    }

    if (ACT == 1) {
        _Float16* ob = (_Float16*)outp + ((size_t)(b * 128 + h) * 128) * 64;
        #pragma unroll
        for (int mt = 0; mt < 2; ++mt) {
            int co_b = wv_m * 32 + mt * 16 + quad * 4;
            #pragma unroll
            for (int nt = 0; nt < 4; ++nt) {
                int px = wv_n * 64 + nt * 16 + l16;
                f16x4 sv;
                #pragma unroll
                for (int r = 0; r < 4; ++r) {
                    float v = acc[mt][nt][r] + bias[co_b + r];
                    v = v > 0.f ? v : 0.1f * v;
                    sv[r] = (_Float16)v;
                }
                *(f16x4*)(ob + px * 64 + co_b) = sv;
            }
        }
    } else {
        _Float16* ob = (_Float16*)outp + (size_t)b * 432 * HW + h * 128;
        #pragma unroll
        for (int mt = 0; mt < 2; ++mt) {
            #pragma unroll
            for (int r = 0; r < 4; ++r) {
                int co = cogB + wv_m * 32 + mt * 16 + quad * 4 + r;
                if (co < 432) {
                    float bv = bias[co];
                    #pragma unroll
                    for (int nt = 0; nt < 4; ++nt) {
                        int px = wv_n * 64 + nt * 16 + l16;
                        float v = acc[mt][nt][r] + bv;
                        if (co < 288) {
                            float e = __expf(2.f * v);
                            v = 10.f * (1.f - 2.f / (e + 1.f));
                        } else {
                            v = 1.f / (1.f + __expf(-v));
                        }
                        ob[(size_t)co * HW + px] = (_Float16)v;
                    }
                }
            }
        }
    }
}

// ---------------------------------------------------------------------------
// deform weight -> fp16 Wp[g][o][kc96], kc = k*8+c, kc>=72 zero-padded.
// ---------------------------------------------------------------------------
__global__ void prep_wp(const float* __restrict__ wsrc, _Float16* __restrict__ wp) {
    int i = blockIdx.x * 256 + threadIdx.x;
    if (i >= 16 * 64 * 96) return;
    int kc = i % 96;
    int go = i / 96;
    int o  = go & 63;
    int g  = go >> 6;
    float v = 0.f;
    if (kc < 72) {
        int k = kc >> 3, c = kc & 7;
        v = wsrc[(o * 128 + g * 8 + c) * 9 + k];
    }
    wp[i] = (_Float16)v;
}

// ---------------------------------------------------------------------------
// Deformable conv, group-split: block = (b,h) x group-quarter (4 groups).
// Grid 2048. Per g: 2 threads/px build V[128px][96kc] fp16 in LDS using
// 16B chunked gathers from xt; k-loop fully unrolled for MLP. Then 4 waves
// MFMA (m-tile=16co each, 8 n-tiles, 3 K-steps). fp16 partial out per gq.
// ---------------------------------------------------------------------------
__global__ __launch_bounds__(256)
void deform_mfma(const _Float16* __restrict__ xt, const _Float16* __restrict__ o4,
                 const _Float16* __restrict__ wp, _Float16* __restrict__ partial) {
    __shared__ char vlds[128 * 256];   // 32 KB: 128 rows x 16 chunks x 16 B
    const int tid  = threadIdx.x;
    const int gq   = blockIdx.x & 3;
    const int bh   = blockIdx.x >> 2;
    const int b    = bh >> 7;
    const int h    = bh & 127;
    const int wv   = tid >> 6;
    const int lane = tid & 63;
    const int quad = lane >> 4;
    const int l16  = lane & 15;

    const int px = tid & 127;          // pixel (V row)
    const int ks = tid >> 7;           // k parity: ks=0 -> k=0,2,4,6,8 ; ks=1 -> 1,3,5,7

    // zero-init all 16 chunks once (logical chunks 9..15 stay zero = K pad)
    {
        f32x4 z = (f32x4){0.f, 0.f, 0.f, 0.f};
        for (int i = tid; i < 2048; i += 256) ((f32x4*)vlds)[i] = z;
    }

    // preload A fragments for this block's 4 groups
    f16x8 aF[4][3];
    #pragma unroll
    for (int gl = 0; gl < 4; ++gl) {
        const _Float16* wg = wp + ((size_t)((gq * 4 + gl) * 64 + wv * 16 + l16)) * 96 + quad * 8;
        #pragma unroll
        for (int s = 0; s < 3; ++s) aF[gl][s] = *(const f16x8*)(wg + s * 32);
    }

    const _Float16* o4p = o4 + (size_t)b * 432 * HW + h * W_ + px;

    f32x4 acc[8];
    #pragma unroll
    for (int nt = 0; nt < 8; ++nt) acc[nt] = (f32x4){0.f, 0.f, 0.f, 0.f};

    #pragma unroll 1
    for (int gl = 0; gl < 4; ++gl) {
        const int g = gq * 4 + gl;
        const _Float16* xg = xt + ((size_t)(b * 16 + g) * HW) * 8;
        __syncthreads();               // prior MFMA reads done (and init, first iter)
        // ---- build V tile: fully unrolled k set ----
        #pragma unroll
        for (int k = ks; k < 9; k += 2) {
            float dy = (float)o4p[(g * 18 + 2 * k) * HW];
            float dx = (float)o4p[(g * 18 + 2 * k + 1) * HW];
            float m  = (float)o4p[(288 + g * 9 + k) * HW];
            float py  = (float)(h - 1 + k / 3) + dy;
            float pxf = (float)(px - 1 + k % 3) + dx;
            float y0f = floorf(py), x0f = floorf(pxf);
            float ly = py - y0f, lx = pxf - x0f;
            int y0 = (int)y0f, x0 = (int)x0f;
            int y1 = y0 + 1,  x1 = x0 + 1;
            float vy0 = ((unsigned)y0 < 128u) ? 1.f : 0.f;
            float vy1 = ((unsigned)y1 < 128u) ? 1.f : 0.f;
            float vx0 = ((unsigned)x0 < 128u) ? 1.f : 0.f;
            float vx1 = ((unsigned)x1 < 128u) ? 1.f : 0.f;
            float w00 = (1.f - ly) * (1.f - lx) * vy0 * vx0 * m;
            float w01 = (1.f - ly) * lx         * vy0 * vx1 * m;
            float w10 = ly * (1.f - lx)         * vy1 * vx0 * m;
            float w11 = ly * lx                 * vy1 * vx1 * m;
            int yc0 = min(max(y0, 0), 127), yc1 = min(max(y1, 0), 127);
            int xc0 = min(max(x0, 0), 127), xc1 = min(max(x1, 0), 127);
            f16x8 c00 = *(const f16x8*)(xg + (yc0 * W_ + xc0) * 8);
            f16x8 c01 = *(const f16x8*)(xg + (yc0 * W_ + xc1) * 8);
            f16x8 c10 = *(const f16x8*)(xg + (yc1 * W_ + xc0) * 8);
            f16x8 c11 = *(const f16x8*)(xg + (yc1 * W_ + xc1) * 8);
            f16x8 vv;
            #pragma unroll
            for (int c = 0; c < 8; ++c) {
                float s = w00 * (float)c00[c] + w01 * (float)c01[c]
                        + w10 * (float)c10[c] + w11 * (float)c11[c];
                vv[c] = (_Float16)s;
            }
            int chunk = k ^ (px & 7);
            *(f16x8*)(vlds + px * 256 + chunk * 16) = vv;
        }
        __syncthreads();               // V visible
        // ---- MFMA ----
        #pragma unroll
        for (int nt = 0; nt < 8; ++nt) {
            int rb = (nt * 16 + l16) * 256;
            int sw = (nt * 16 + l16) & 7;
            #pragma unroll
            for (int s = 0; s < 3; ++s) {
                f16x8 bF = *(const f16x8*)(vlds + rb + (((s << 2) + quad) ^ sw) * 16);
                acc[nt] = __builtin_amdgcn_mfma_f32_16x16x32_f16(aF[gl][s], bF, acc[nt], 0, 0, 0);
            }
        }
    }

    // ---- partial store (fp16, no bias): partial[gq][b][o][hw] ----
    const int obase = wv * 16 + quad * 4;
    #pragma unroll
    for (int r = 0; r < 4; ++r) {
        _Float16* po = partial + (((size_t)gq * 4 + b) * 64 + obase + r) * HW + h * W_ + l16;
        #pragma unroll
        for (int nt = 0; nt < 8; ++nt) {
            po[nt * 16] = (_Float16)acc[nt][r];
        }
    }
}

// ---------------------------------------------------------------------------
// out = bias + sum of 4 fp16 partials. 8 elems/thread.
// ---------------------------------------------------------------------------
__global__ __launch_bounds__(256)
void reduce_out(const _Float16* __restrict__ p, const float* __restrict__ bias,
                float* __restrict__ out) {
    const int i8 = (blockIdx.x * 256 + threadIdx.x) * 8;   // over 4*64*16384
    const int o  = (i8 >> 14) & 63;
    const float bv = bias[o];
    f16x8 a = *(const f16x8*)(p + i8);
    f16x8 b = *(const f16x8*)(p + i8 + 4194304);
    f16x8 c = *(const f16x8*)(p + i8 + 8388608);
    f16x8 d = *(const f16x8*)(p + i8 + 12582912);
    float4 o0, o1;
    float t[8];
    #pragma unroll
    for (int j = 0; j < 8; ++j)
        t[j] = bv + (float)a[j] + (float)b[j] + (float)c[j] + (float)d[j];
    o0 = make_float4(t[0], t[1], t[2], t[3]);
    o1 = make_float4(t[4], t[5], t[6], t[7]);
    *(float4*)(out + i8)     = o0;
    *(float4*)(out + i8 + 4) = o1;
}

// ---------------------------------------------------------------------------
extern "C" void kernel_launch(void* const* d_in, const int* in_sizes, int n_in,
                              void* d_out, int out_size, void* d_ws, size_t ws_size,
                              hipStream_t stream) {
    const float* x  = (const float*)d_in[0];
    const float* ef = (const float*)d_in[1];
    const float* w1 = (const float*)d_in[2];
    const float* b1 = (const float*)d_in[3];
    const float* w2 = (const float*)d_in[4];
    const float* b2 = (const float*)d_in[5];
    const float* w3 = (const float*)d_in[6];
    const float* b3 = (const float*)d_in[7];
    const float* w4 = (const float*)d_in[8];
    const float* b4 = (const float*)d_in[9];
    const float* wd = (const float*)d_in[10];
    const float* bd = (const float*)d_in[11];
    float* out = (float*)d_out;

    char* ws = (char*)d_ws;
    // partial (33,554,432 B) overlays ef_t+tA — both dead before deform runs.
    _Float16* ef_t = (_Float16*)(ws);                     // 25,165,824 B
    _Float16* part = (_Float16*)(ws);                     // 33,554,432 B (deform phase)
    _Float16* tA   = (_Float16*)(ws + 25165824);          //  8,388,608 B
    _Float16* tB   = (_Float16*)(ws + 33554432);          //  8,388,608 B
    _Float16* o4h  = (_Float16*)(ws + 41943040);          // 56,623,104 B
    _Float16* wpd  = (_Float16*)(ws + 98566144);          //    196,608 B
    _Float16* A1   = (_Float16*)(ws + 98762752);          //    221,184 B
    _Float16* A2   = (_Float16*)(ws + 98983936);          //     73,728 B
    _Float16* A3   = (_Float16*)(ws + 99057664);          //     73,728 B
    _Float16* A4   = (_Float16*)(ws + 99131392);          //    516,096 B
    _Float16* xtb  = (_Float16*)(ws + 99647488);          // 16,777,216 B -> ends 116,424,704

    prep_wp<<<384, 256, 0, stream>>>(wd, wpd);
    prep_convA<<<432, 256, 0, stream>>>(w1, A1, 192, 64, 64);
    prep_convA<<<144, 256, 0, stream>>>(w2, A2, 64, 64, 64);
    prep_convA<<<144, 256, 0, stream>>>(w3, A3, 64, 64, 64);
    prep_convA<<<1008, 256, 0, stream>>>(w4, A4, 64, 432, 448);
    transpose_x<<<4096, 256, 0, stream>>>(x, xtb);
    transpose_ef<<<512, 256, 0, stream>>>(ef, ef_t);

    conv_mfma<192, 64, 1><<<dim3(512, 1), 256, 0, stream>>>(ef_t, A1, b1, tA);
    conv_mfma< 64, 64, 1><<<dim3(512, 1), 256, 0, stream>>>(tA, A2, b2, tB);
    conv_mfma< 64, 64, 1><<<dim3(512, 1), 256, 0, stream>>>(tB, A3, b3, tA);
    conv_mfma< 64, 448, 2><<<dim3(512, 7), 256, 0, stream>>>(tA, A4, b4, o4h);

    deform_mfma<<<2048, 256, 0, stream>>>(xtb, o4h, wpd, part);
    reduce_out<<<2048, 256, 0, stream>>>(part, bd, out);
}